// Round 6
// baseline (341.041 us; speedup 1.0000x reference)
//
#include <hip/hip_runtime.h>
#include <hip/hip_fp16.h>
#include <math.h>

// Problem constants (match reference)
#define NN     50000
#define EE     800000
#define ETOT   (EE + NN)      // edges + self loops = 850000
#define INDIM  128
#define HEADS  4
#define NG     128
#define NEGS   0.2f
#define BNEPS  1e-5f

typedef _Float16 half8 __attribute__((ext_vector_type(8)));
typedef _Float16 half4v __attribute__((ext_vector_type(4)));
typedef float floatx4 __attribute__((ext_vector_type(4)));

// R20: CSR build WITHOUT global atomics. R19 counters proved the 54us degree
// dispatch is a memory-side-atomic wall (WRITE_SIZE 38MB >> 15MB real stores
// = per-op write-through; padding didn't help; overlap didn't help). Replace
// atomicAdd-rank with a 2-pass MSB counting sort using LDS atomics only:
//   hist (d>>8, 128 blocks, LDS)        -> fused into prep dispatch
//   scan1 (1 block scans 256x128 hists) -> absolute offsets
//   scatter1 ((d,src) -> bin-grouped tmp, LDS-ranked) -> fused with gemm0
//   pass2 (1 block/bin: low-byte LDS hist + scan -> rowstart + final csr)
// rank/deg arrays deleted. 11 dispatches:
//   prep||hist; scan1; gemm0||scatter1; pass2; aggr0; gemm1||alpha; aggr1;
//   gemm2; aggr2; pool; fc.

#define GEMMB  ((NN + 63) / 64)        // 782
#define HB     128                     // hist / scatter1 blocks
#define EPB    ((ETOT + HB - 1) / HB)  // 6641 edges per hist block
#define PASS2B ((NN + 255) / 256)      // 196 coarse bins in use

#define NX8    (NN * INDIM / 8)        // 800000
#define PW1    (NX8 + 2048)            // + W 8-groups
#define PW2    (PW1 + NG * 64)
#define PW3    (PW2 + NG)
#define PREPWB ((PW3 + 255) / 256)     // 3166 prep-work blocks

// edge e -> (src, dst) including appended self loops
__device__ __forceinline__ int edge_dst(const int* __restrict__ ei, int e) {
    return (e < EE) ? ei[EE + e] : (e - EE);
}
__device__ __forceinline__ int edge_src(const int* __restrict__ ei, int e) {
    return (e < EE) ? ei[e] : (e - EE);
}

// ---------------------------------------------------------------------------
// Dispatch 1: prep (fp32->fp16 X/W converts + psums/pcnt zero) || coarse hist.
// bh layout: bh[bin*HB + blk], bin-major so scan1 reads it linearly.
__global__ __launch_bounds__(256) void prep_hist_kernel(
    const float* __restrict__ x, const float* __restrict__ W0,
    const float* __restrict__ W1, const float* __restrict__ W2,
    _Float16* __restrict__ Xh, _Float16* __restrict__ Wh,
    float* __restrict__ psums, int* __restrict__ pcnt,
    const int* __restrict__ ei, int* __restrict__ bh) {
    __shared__ int hist[256];
    int bid = blockIdx.x;
    int tid = threadIdx.x;
    if (bid < PREPWB) {
        int i = bid * 256 + tid;
        if (i < NX8) {
            float4 v0 = *(const float4*)(x + (size_t)i * 8);
            float4 v1 = *(const float4*)(x + (size_t)i * 8 + 4);
            half8 o;
            o[0] = (_Float16)v0.x; o[1] = (_Float16)v0.y;
            o[2] = (_Float16)v0.z; o[3] = (_Float16)v0.w;
            o[4] = (_Float16)v1.x; o[5] = (_Float16)v1.y;
            o[6] = (_Float16)v1.z; o[7] = (_Float16)v1.w;
            *(half8*)(Xh + (size_t)i * 8) = o;
        } else if (i < PW1) {
            int wi = (i - NX8) * 8;        // 8-groups never straddle W arrays
#pragma unroll
            for (int j = 0; j < 8; ++j) {
                int idx = wi + j;
                float v = (idx < 8192) ? W0[idx]
                        : ((idx < 12288) ? W1[idx - 8192] : W2[idx - 12288]);
                Wh[idx] = (_Float16)v;
            }
        } else if (i < PW2) {
            psums[i - PW1] = 0.f;
        } else if (i < PW3) {
            pcnt[i - PW2] = 0;
        }
    } else {
        int hb = bid - PREPWB;             // 0..HB-1
        hist[tid] = 0;
        __syncthreads();
        int base = hb * EPB;
        int end = min(base + EPB, ETOT);
        for (int e = base + tid; e < end; e += 256)
            atomicAdd(&hist[edge_dst(ei, e) >> 8], 1);
        __syncthreads();
        bh[tid * HB + hb] = hist[tid];     // tid == bin
    }
}

// ---------------------------------------------------------------------------
// Dispatch 2: single-block exclusive scan of bh (256*HB = 32768 ints),
// 32 chunks of 1024. Leaves bh[bin*HB+blk] = absolute start offset.
__global__ __launch_bounds__(1024) void scan1_kernel(int* __restrict__ bh,
                                                     int* __restrict__ rowstart) {
    __shared__ int wsum[16];
    __shared__ int carryS;
    int tid = threadIdx.x;
    int lane = tid & 63;
    int w = tid >> 6;
    if (tid == 0) carryS = 0;
    __syncthreads();
    for (int c = 0; c < 32; ++c) {
        int idx = c * 1024 + tid;
        int v = bh[idx];
        int x = v;
#pragma unroll
        for (int off = 1; off < 64; off <<= 1) {
            int t = __shfl_up(x, off, 64);
            if (lane >= off) x += t;
        }
        if (lane == 63) wsum[w] = x;
        __syncthreads();
        if (w == 0 && lane < 16) {
            int s = wsum[lane];
#pragma unroll
            for (int off = 1; off < 16; off <<= 1) {
                int t = __shfl_up(s, off, 16);
                if ((lane & 15) >= off) s += t;
            }
            wsum[lane] = s;
        }
        __syncthreads();
        int incl = ((w > 0) ? wsum[w - 1] : 0) + x;
        int c0 = carryS;
        bh[idx] = c0 + incl - v;           // exclusive absolute offset
        __syncthreads();                   // all carryS reads done
        if (tid == 1023) carryS = c0 + incl;
        __syncthreads();
    }
    if (tid == 0) rowstart[NN] = ETOT;
}

// ---------------------------------------------------------------------------
// MFMA GEMM (h = x @ W^T) + attention dots. 4 waves/block; wave owns 16 nodes
// x 64 cols (4 col-tiles of 16x16), K in 32-chunks. AD written into packed
// ADZ rows (stride 8): [0..3]=AD, [4..7]=Z.
template <int DD>
__device__ __forceinline__ void gemm_att_body(
    int bid, const _Float16* __restrict__ X, const _Float16* __restrict__ Wh,
    const float* __restrict__ attS, const float* __restrict__ attD,
    _Float16* __restrict__ H, float* __restrict__ AS, float* __restrict__ ADZ) {
    constexpr int KB = DD / 32;
    int tid = threadIdx.x;
    int wv = tid >> 6;
    int lane = tid & 63;
    int quad = lane >> 4;
    int n = lane & 15;
    int wbase = bid * 64 + wv * 16;

    int arow = wbase + n;
    if (arow >= NN) arow = NN - 1;          // clamp (stores are guarded)
    half8 a[KB];
#pragma unroll
    for (int kb = 0; kb < KB; ++kb)
        a[kb] = *(const half8*)(X + (size_t)arow * DD + kb * 32 + quad * 8);

    floatx4 c[4];
#pragma unroll
    for (int t = 0; t < 4; ++t) {
        floatx4 acc = {0.f, 0.f, 0.f, 0.f};
#pragma unroll
        for (int kb = 0; kb < KB; ++kb) {
            half8 b = *(const half8*)(Wh + (size_t)(t * 16 + n) * DD + kb * 32 + quad * 8);
            acc = __builtin_amdgcn_mfma_f32_16x16x32_f16(a[kb], b, acc, 0, 0, 0);
        }
        c[t] = acc;
    }

    float as_l[4], ad_l[4];
#pragma unroll
    for (int t = 0; t < 4; ++t) {
        as_l[t] = attS[t * 16 + n];
        ad_l[t] = attD[t * 16 + n];
    }
#pragma unroll
    for (int r = 0; r < 4; ++r) {
        int node = wbase + quad * 4 + r;
        bool ok = node < NN;
#pragma unroll
        for (int t = 0; t < 4; ++t) {
            float h = c[t][r];
            if (ok) H[(size_t)node * 64 + t * 16 + n] = (_Float16)h;
            float vs = h * as_l[t];
            float vd = h * ad_l[t];
#pragma unroll
            for (int off = 8; off; off >>= 1) {
                vs += __shfl_down(vs, off, 16);
                vd += __shfl_down(vd, off, 16);
            }
            if (ok && n == 0) {
                AS[node * 4 + t] = vs;
                ADZ[(size_t)node * 8 + t] = vd;
            }
        }
    }
}

// Dispatch 3: gemm layer 0 (K=128, needs prep) || scatter1 (needs scan1).
// scatter1: LDS-ranked scatter of (d,src) into bin-grouped tmp. Any order
// within a bin is fine (grouping only; aggregation is order-tolerant).
__global__ __launch_bounds__(256) void gemm0_scatter1_kernel(
    const _Float16* __restrict__ X, const _Float16* __restrict__ Wh,
    const float* __restrict__ attS, const float* __restrict__ attD,
    _Float16* __restrict__ H, float* __restrict__ AS, float* __restrict__ ADZ,
    const int* __restrict__ ei, const int* __restrict__ bh,
    int2* __restrict__ tmp) {
    __shared__ int offs[256];
    if (blockIdx.x < GEMMB) {
        gemm_att_body<128>(blockIdx.x, X, Wh, attS, attD, H, AS, ADZ);
    } else {
        int sb = blockIdx.x - GEMMB;       // 0..HB-1
        int tid = threadIdx.x;
        offs[tid] = bh[tid * HB + sb];     // absolute start for (bin, this blk)
        __syncthreads();
        int base = sb * EPB;
        int end = min(base + EPB, ETOT);
        for (int e = base + tid; e < end; e += 256) {
            int d = edge_dst(ei, e);
            int s = edge_src(ei, e);
            int pos = atomicAdd(&offs[d >> 8], 1);   // LDS atomic (fast)
            int2 p; p.x = d; p.y = s;
            tmp[pos] = p;
        }
    }
}

// ---------------------------------------------------------------------------
// Dispatch 4: pass2 — one block per coarse bin. Low-byte LDS hist + scan:
// writes rowstart for the bin's 256 nodes and the final csr (src grouped by d).
__global__ __launch_bounds__(256) void pass2_kernel(
    const int2* __restrict__ tmp, const int* __restrict__ bh,
    int* __restrict__ csr, int* __restrict__ rowstart) {
    __shared__ int h2[256];
    __shared__ int offs[256];
    __shared__ int ws[4];
    int b = blockIdx.x;                    // coarse bin
    int tid = threadIdx.x;
    int lane = tid & 63;
    int w = tid >> 6;
    int A = bh[b * HB];                    // segment [A, Bend)
    int Bend = bh[(b + 1) * HB];
    h2[tid] = 0;
    __syncthreads();
    for (int idx = A + tid; idx < Bend; idx += 256)
        atomicAdd(&h2[tmp[idx].x & 255], 1);
    __syncthreads();
    int v = h2[tid];
    int x = v;
#pragma unroll
    for (int off = 1; off < 64; off <<= 1) {
        int t = __shfl_up(x, off, 64);
        if (lane >= off) x += t;
    }
    if (lane == 63) ws[w] = x;
    __syncthreads();
    if (tid == 0) {
        int s = 0;
#pragma unroll
        for (int j = 0; j < 4; ++j) { int t = ws[j]; ws[j] = s; s += t; }
    }
    __syncthreads();
    int ex = x - v + ws[w];                // exclusive within segment
    int abs0 = A + ex;
    offs[tid] = abs0;
    int d = b * 256 + tid;
    if (d < NN) rowstart[d] = abs0;
    __syncthreads();
    for (int idx = A + tid; idx < Bend; idx += 256) {
        int2 p = tmp[idx];
        int pos = atomicAdd(&offs[p.x & 255], 1);
        csr[pos] = p.y;
    }
}

// ---------------------------------------------------------------------------
// Layer-0 alpha, ORIGINAL edge order: recomputes p from AS/ADZ (identical
// formula+inputs as aggr => identical values), divides by Z, coalesced float4
// store. AD and Z share one 32B row -> one cache line per dst lookup.
__device__ __forceinline__ void alpha_body(
    int bid, const int* __restrict__ ei, const float* __restrict__ AS,
    const float* __restrict__ ADZ, float* __restrict__ alpha_out) {
    int e = bid * 256 + threadIdx.x;
    if (e >= ETOT) return;
    int s = edge_src(ei, e);
    int d = edge_dst(ei, e);
    float4 as = *(const float4*)(AS + (size_t)s * 4);
    const float* row = ADZ + (size_t)d * 8;
    float4 ad = *(const float4*)(row);
    float4 z4 = *(const float4*)(row + 4);
    float l;
    float4 a;
    l = as.x + ad.x; l = l > 0.f ? l : NEGS * l; a.x = __expf(l) / z4.x;
    l = as.y + ad.y; l = l > 0.f ? l : NEGS * l; a.y = __expf(l) / z4.y;
    l = as.z + ad.z; l = l > 0.f ? l : NEGS * l; a.z = __expf(l) / z4.z;
    l = as.w + ad.w; l = l > 0.f ? l : NEGS * l; a.w = __expf(l) / z4.w;
    *(float4*)(alpha_out + (size_t)e * 4) = a;
}

#define SCATB  ((ETOT + 255) / 256)    // 3321 (alpha blocks)

// Merged: gemm layer 1 (K=64, writes b-buffers) + layer-0 alpha (reads
// a-buffers) — no overlap thanks to AS/ADZ double buffering.
__global__ __launch_bounds__(256) void gemm1_alpha_kernel(
    const _Float16* __restrict__ X, const _Float16* __restrict__ Wh,
    const float* __restrict__ attS, const float* __restrict__ attD,
    _Float16* __restrict__ H, float* __restrict__ ASb, float* __restrict__ ADZb,
    const int* __restrict__ ei, const float* __restrict__ ASa,
    const float* __restrict__ ADZa, float* __restrict__ alpha_out) {
    if (blockIdx.x < GEMMB)
        gemm_att_body<64>(blockIdx.x, X, Wh, attS, attD, H, ASb, ADZb);
    else
        alpha_body(blockIdx.x - GEMMB, ei, ASa, ADZa, alpha_out);
}

__global__ __launch_bounds__(256) void gemm2_kernel(
    const _Float16* __restrict__ X, const _Float16* __restrict__ Wh,
    const float* __restrict__ attS, const float* __restrict__ attD,
    _Float16* __restrict__ H, float* __restrict__ AS, float* __restrict__ ADZ) {
    gemm_att_body<64>(blockIdx.x, X, Wh, attS, attD, H, AS, ADZ);
}

// ---------------------------------------------------------------------------
// Per-node aggregation, quarter-wave edge parallelism, single masked 16-wide
// loop (clamped index + p=0 mask).
template <bool WRITE_Z>
__global__ __launch_bounds__(256) void edge_aggr_kernel(
    const _Float16* __restrict__ H, const float* __restrict__ AS,
    float* __restrict__ ADZ,
    const int* __restrict__ rowstart,
    const int* __restrict__ csr,
    const float* __restrict__ bias, const float* __restrict__ gamma,
    const float* __restrict__ beta, const float* __restrict__ mean,
    const float* __restrict__ var, _Float16* __restrict__ Hout) {
    int v = (blockIdx.x * blockDim.x + threadIdx.x) >> 6;
    if (v >= NN) return;
    int lane = threadIdx.x & 63;
    int q = lane >> 4;
    int l16 = lane & 15;
    int head = l16 >> 2;
    int ch4 = l16 * 4;
    float adv = ADZ[(size_t)v * 8 + head];
    int start = rowstart[v];
    int cnt = rowstart[v + 1] - start;   // >= 1 (self loop)
    const int* srow = csr + start;
    int cm1 = cnt - 1;
    float z = 0.f;
    float acc0 = 0.f, acc1 = 0.f, acc2 = 0.f, acc3 = 0.f;
    for (int k = 0; k < cnt; k += 16) {
        int b = k + q * 4;
        int s0 = srow[min(b + 0, cm1)];
        int s1 = srow[min(b + 1, cm1)];
        int s2 = srow[min(b + 2, cm1)];
        int s3 = srow[min(b + 3, cm1)];
        float a0 = AS[(size_t)s0 * 4 + head];
        float a1 = AS[(size_t)s1 * 4 + head];
        float a2 = AS[(size_t)s2 * 4 + head];
        float a3 = AS[(size_t)s3 * 4 + head];
        half4v h0 = *(const half4v*)(H + (size_t)s0 * 64 + ch4);
        half4v h1 = *(const half4v*)(H + (size_t)s1 * 64 + ch4);
        half4v h2 = *(const half4v*)(H + (size_t)s2 * 64 + ch4);
        half4v h3 = *(const half4v*)(H + (size_t)s3 * 64 + ch4);
        float l0 = a0 + adv; l0 = l0 > 0.f ? l0 : NEGS * l0;
        float l1 = a1 + adv; l1 = l1 > 0.f ? l1 : NEGS * l1;
        float l2 = a2 + adv; l2 = l2 > 0.f ? l2 : NEGS * l2;
        float l3 = a3 + adv; l3 = l3 > 0.f ? l3 : NEGS * l3;
        float p0 = (b + 0 < cnt) ? __expf(l0) : 0.f;
        float p1 = (b + 1 < cnt) ? __expf(l1) : 0.f;
        float p2 = (b + 2 < cnt) ? __expf(l2) : 0.f;
        float p3 = (b + 3 < cnt) ? __expf(l3) : 0.f;
        z += (p0 + p1) + (p2 + p3);
        acc0 = fmaf(p0, (float)h0[0], acc0); acc1 = fmaf(p0, (float)h0[1], acc1);
        acc2 = fmaf(p0, (float)h0[2], acc2); acc3 = fmaf(p0, (float)h0[3], acc3);
        acc0 = fmaf(p1, (float)h1[0], acc0); acc1 = fmaf(p1, (float)h1[1], acc1);
        acc2 = fmaf(p1, (float)h1[2], acc2); acc3 = fmaf(p1, (float)h1[3], acc3);
        acc0 = fmaf(p2, (float)h2[0], acc0); acc1 = fmaf(p2, (float)h2[1], acc1);
        acc2 = fmaf(p2, (float)h2[2], acc2); acc3 = fmaf(p2, (float)h2[3], acc3);
        acc0 = fmaf(p3, (float)h3[0], acc0); acc1 = fmaf(p3, (float)h3[1], acc1);
        acc2 = fmaf(p3, (float)h3[2], acc2); acc3 = fmaf(p3, (float)h3[3], acc3);
    }
    // combine the four quarter-wave partial sums
    z    += __shfl_xor(z, 16);    z    += __shfl_xor(z, 32);
    acc0 += __shfl_xor(acc0, 16); acc0 += __shfl_xor(acc0, 32);
    acc1 += __shfl_xor(acc1, 16); acc1 += __shfl_xor(acc1, 32);
    acc2 += __shfl_xor(acc2, 16); acc2 += __shfl_xor(acc2, 32);
    acc3 += __shfl_xor(acc3, 16); acc3 += __shfl_xor(acc3, 32);
    if (q == 0) {
        if (WRITE_Z && (l16 & 3) == 0) ADZ[(size_t)v * 8 + 4 + head] = z;
        float4 bi = *(const float4*)(bias + ch4);
        float4 ga = *(const float4*)(gamma + ch4);
        float4 be = *(const float4*)(beta + ch4);
        float4 mu = *(const float4*)(mean + ch4);
        float4 va = *(const float4*)(var + ch4);
        float r0 = fmaxf(acc0 / z + bi.x, 0.f);
        float r1 = fmaxf(acc1 / z + bi.y, 0.f);
        float r2 = fmaxf(acc2 / z + bi.z, 0.f);
        float r3 = fmaxf(acc3 / z + bi.w, 0.f);
        r0 = ga.x * (r0 - mu.x) * rsqrtf(va.x + BNEPS) + be.x;
        r1 = ga.y * (r1 - mu.y) * rsqrtf(va.y + BNEPS) + be.y;
        r2 = ga.z * (r2 - mu.z) * rsqrtf(va.z + BNEPS) + be.z;
        r3 = ga.w * (r3 - mu.w) * rsqrtf(va.w + BNEPS) + be.w;
        half4v o;
        o[0] = (_Float16)r0;
        o[1] = (_Float16)r1;
        o[2] = (_Float16)r2;
        o[3] = (_Float16)r3;
        *(half4v*)(Hout + (size_t)v * 64 + ch4) = o;
    }
}

// ---------------------------------------------------------------------------
// Mean pool over sorted batch ids (fp16 input): one wave per 16-node chunk,
// local accumulation, atomic flush on graph-id change (max ~25 collisions
// per address — measured fine; do NOT fuse into aggr as per-node atomics).
__global__ __launch_bounds__(256) void pool_kernel(const __half* __restrict__ H,
                                                   const int* __restrict__ batch,
                                                   float* __restrict__ sums,
                                                   int* __restrict__ cnt) {
    int wid = (blockIdx.x * blockDim.x + threadIdx.x) >> 6;
    int lane = threadIdx.x & 63;
    int base = wid * 16;
    if (base >= NN) return;
    int end = min(base + 16, NN);
    int cur = batch[base];
    float acc = 0.f;
    int c0 = 0;
    for (int i = base; i < end; ++i) {
        int g = batch[i];
        if (g != cur) {
            atomicAdd(&sums[cur * 64 + lane], acc);
            if (lane == 0) atomicAdd(&cnt[cur], c0);
            cur = g; acc = 0.f; c0 = 0;
        }
        acc += __half2float(H[(size_t)i * 64 + lane]);
        c0++;
    }
    atomicAdd(&sums[cur * 64 + lane], acc);
    if (lane == 0) atomicAdd(&cnt[cur], c0);
}

__global__ void fc_kernel(const float* __restrict__ sums, const int* __restrict__ cnt,
                          const float* __restrict__ fcW, const float* __restrict__ fcb,
                          float* __restrict__ out) {
    int g = (blockIdx.x * blockDim.x + threadIdx.x) >> 6;
    int lane = threadIdx.x & 63;
    if (g >= NG) return;
    float c = fmaxf((float)cnt[g], 1.f);
    float val = (sums[g * 64 + lane] / c) * fcW[lane];
#pragma unroll
    for (int off = 32; off; off >>= 1) val += __shfl_down(val, off, 64);
    if (lane == 0) out[g] = 1.f / (1.f + expf(-(val + fcb[0])));
}

// ---------------------------------------------------------------------------
extern "C" void kernel_launch(void* const* d_in, const int* in_sizes, int n_in,
                              void* d_out, int out_size, void* d_ws, size_t ws_size,
                              hipStream_t stream) {
    const float* x   = (const float*)d_in[0];
    const int* ei    = (const int*)d_in[1];
    const int* batch = (const int*)d_in[2];
    const float* W[3], *attS[3], *attD[3], *bias[3], *gamma[3], *beta[3], *mean[3], *var[3];
    for (int l = 0; l < 3; ++l) {
        W[l]     = (const float*)d_in[3 + 8 * l + 0];
        attS[l]  = (const float*)d_in[3 + 8 * l + 1];
        attD[l]  = (const float*)d_in[3 + 8 * l + 2];
        bias[l]  = (const float*)d_in[3 + 8 * l + 3];
        gamma[l] = (const float*)d_in[3 + 8 * l + 4];
        beta[l]  = (const float*)d_in[3 + 8 * l + 5];
        mean[l]  = (const float*)d_in[3 + 8 * l + 6];
        var[l]   = (const float*)d_in[3 + 8 * l + 7];
    }
    const float* fcW = (const float*)d_in[27];
    const float* fcb = (const float*)d_in[28];
    float* out = (float*)d_out;               // [128] pooled sigmoid
    float* alpha_out = (float*)d_out + NG;    // [850000*4] layer-0 alpha

    // Workspace carve-up (256B aligned)
    char* p = (char*)d_ws;
    auto carve = [&](size_t bytes) {
        char* q = p;
        p += (bytes + 255) & ~(size_t)255;
        return q;
    };
    _Float16* Xh    = (_Float16*)carve(sizeof(_Float16) * NN * INDIM);
    _Float16* Wh    = (_Float16*)carve(sizeof(_Float16) * 16384);
    _Float16* Hh    = (_Float16*)carve(sizeof(_Float16) * NN * 64);  // gemm out
    _Float16* Hn    = (_Float16*)carve(sizeof(_Float16) * NN * 64);  // aggr out
    float* ASa      = (float*)carve(sizeof(float) * NN * 4);   // layers 0,2
    float* ADZa     = (float*)carve(sizeof(float) * NN * 8);   // [0..3]=AD [4..7]=Z
    float* ASb      = (float*)carve(sizeof(float) * NN * 4);   // layer 1
    float* ADZb     = (float*)carve(sizeof(float) * NN * 8);
    int*   rowstart = (int*)carve(sizeof(int) * (NN + 1));
    int*   bh       = (int*)carve(sizeof(int) * 256 * HB);     // bin-major hists
    int2*  tmp      = (int2*)carve(sizeof(int2) * ETOT);       // (d,src) pass-1
    int*   csr      = (int*)carve(sizeof(int) * ETOT);
    float* psums    = (float*)carve(sizeof(float) * NG * 64);
    int*   pcnt     = (int*)carve(sizeof(int) * NG);

    int edgeBlocks = (NN * 64 + 255) / 256;

    // 1. prep (X/W converts, psums/pcnt zero) || coarse histogram (LDS)
    prep_hist_kernel<<<PREPWB + HB, 256, 0, stream>>>(
        x, W[0], W[1], W[2], Xh, Wh, psums, pcnt, ei, bh);

    // 2. scan of block histograms -> absolute offsets (+ rowstart[NN])
    scan1_kernel<<<1, 1024, 0, stream>>>(bh, rowstart);

    // 3. gemm layer 0 || bin-grouping scatter into tmp (LDS-ranked)
    gemm0_scatter1_kernel<<<GEMMB + HB, 256, 0, stream>>>(
        Xh, Wh, attS[0], attD[0], Hh, ASa, ADZa, ei, bh, tmp);

    // 4. per-bin low-byte sort -> rowstart + final csr (no global atomics)
    pass2_kernel<<<PASS2B, 256, 0, stream>>>(tmp, bh, csr, rowstart);

    // 5. aggr layer 0 (writes Z into ADZa, Hn)
    edge_aggr_kernel<true><<<edgeBlocks, 256, 0, stream>>>(
        Hh, ASa, ADZa, rowstart, csr,
        bias[0], gamma[0], beta[0], mean[0], var[0], Hn);

    // 6. gemm layer 1 (b-buffers) || layer-0 alpha (a-buffers)
    gemm1_alpha_kernel<<<GEMMB + SCATB, 256, 0, stream>>>(
        Hn, Wh + 8192, attS[1], attD[1], Hh, ASb, ADZb,
        ei, ASa, ADZa, alpha_out);

    // 7. aggr layer 1
    edge_aggr_kernel<false><<<edgeBlocks, 256, 0, stream>>>(
        Hh, ASb, ADZb, rowstart, csr,
        bias[1], gamma[1], beta[1], mean[1], var[1], Hn);

    // 8. gemm layer 2 (a-buffers again — alpha completed in step 6)
    gemm2_kernel<<<GEMMB, 256, 0, stream>>>(
        Hn, Wh + 12288, attS[2], attD[2], Hh, ASa, ADZa);

    // 9. aggr layer 2 -> Hn
    edge_aggr_kernel<false><<<edgeBlocks, 256, 0, stream>>>(
        Hh, ASa, ADZa, rowstart, csr,
        bias[2], gamma[2], beta[2], mean[2], var[2], Hn);

    // 10. pool (streaming, low-contention flush atomics)
    int poolWaves = (NN + 15) / 16;
    pool_kernel<<<(poolWaves * 64 + 255) / 256, 256, 0, stream>>>(
        (const __half*)Hn, batch, psums, pcnt);

    // 11. FC
    fc_kernel<<<(NG * 64 + 255) / 256, 256, 0, stream>>>(psums, pcnt, fcW, fcb, out);
}

// Round 7
// 312.672 us; speedup vs baseline: 1.0907x; 1.0907x over previous
//
#include <hip/hip_runtime.h>
#include <hip/hip_fp16.h>
#include <math.h>

// Problem constants (match reference)
#define NN     50000
#define EE     800000
#define ETOT   (EE + NN)      // edges + self loops = 850000
#define INDIM  128
#define HEADS  4
#define NG     128
#define NEGS   0.2f
#define BNEPS  1e-5f

typedef _Float16 half8 __attribute__((ext_vector_type(8)));
typedef _Float16 half4v __attribute__((ext_vector_type(4)));
typedef float floatx4 __attribute__((ext_vector_type(4)));

// R21: R20's LDS-sort CSR kept, implementation fixed (R20=341 vs R18=330:
// sort pipeline cost ~65us, model said 25 — scan1 had 96 barriers + serial
// carry; pass2 was 196 blocks x 4 waves with two dependent global passes).
//  (1) bh block-major -> all accesses coalesced.
//  (2) scan1 v2: 1 thread/bin walks its 128 counts; 2 barriers (was 96).
//  (3) pass2 v2: 512 thr, segment staged in LDS once, rank+scatter in LDS,
//      coalesced csr write; global-path fallback if seg > cap (never on
//      uniform-random input: mean 4330, sigma 66, cap 6144).
//  (4) tmp packed 4B/edge: (d&255)<<16 | s  (s < 2^16 since NN=50000).
// Schedule (11 ops): prep||hist; scan1; gemm0||scatter1; pass2; aggr0;
// gemm1||alpha; aggr1; gemm2; aggr2; pool; fc.

#define GEMMB  ((NN + 63) / 64)        // 782
#define HB     128                     // hist / scatter1 blocks
#define EPB    ((ETOT + HB - 1) / HB)  // 6641 edges per hist block
#define PASS2B ((NN + 255) / 256)      // 196 coarse bins in use
#define SEGCAP 6144                    // pass2 LDS segment capacity

#define NX8    (NN * INDIM / 8)        // 800000
#define PW1    (NX8 + 2048)            // + W 8-groups
#define PW2    (PW1 + NG * 64)
#define PW3    (PW2 + NG)
#define PREPWB ((PW3 + 255) / 256)     // prep-work blocks

// edge e -> (src, dst) including appended self loops
__device__ __forceinline__ int edge_dst(const int* __restrict__ ei, int e) {
    return (e < EE) ? ei[EE + e] : (e - EE);
}
__device__ __forceinline__ int edge_src(const int* __restrict__ ei, int e) {
    return (e < EE) ? ei[e] : (e - EE);
}

// ---------------------------------------------------------------------------
// Dispatch 1: prep (fp32->fp16 X/W converts + psums/pcnt zero) || coarse hist.
// bh layout: bh[blk*256 + bin] (block-major) — coalesced everywhere.
__global__ __launch_bounds__(256) void prep_hist_kernel(
    const float* __restrict__ x, const float* __restrict__ W0,
    const float* __restrict__ W1, const float* __restrict__ W2,
    _Float16* __restrict__ Xh, _Float16* __restrict__ Wh,
    float* __restrict__ psums, int* __restrict__ pcnt,
    const int* __restrict__ ei, int* __restrict__ bh) {
    __shared__ int hist[256];
    int bid = blockIdx.x;
    int tid = threadIdx.x;
    if (bid < PREPWB) {
        int i = bid * 256 + tid;
        if (i < NX8) {
            float4 v0 = *(const float4*)(x + (size_t)i * 8);
            float4 v1 = *(const float4*)(x + (size_t)i * 8 + 4);
            half8 o;
            o[0] = (_Float16)v0.x; o[1] = (_Float16)v0.y;
            o[2] = (_Float16)v0.z; o[3] = (_Float16)v0.w;
            o[4] = (_Float16)v1.x; o[5] = (_Float16)v1.y;
            o[6] = (_Float16)v1.z; o[7] = (_Float16)v1.w;
            *(half8*)(Xh + (size_t)i * 8) = o;
        } else if (i < PW1) {
            int wi = (i - NX8) * 8;        // 8-groups never straddle W arrays
#pragma unroll
            for (int j = 0; j < 8; ++j) {
                int idx = wi + j;
                float v = (idx < 8192) ? W0[idx]
                        : ((idx < 12288) ? W1[idx - 8192] : W2[idx - 12288]);
                Wh[idx] = (_Float16)v;
            }
        } else if (i < PW2) {
            psums[i - PW1] = 0.f;
        } else if (i < PW3) {
            pcnt[i - PW2] = 0;
        }
    } else {
        int hb = bid - PREPWB;             // 0..HB-1
        hist[tid] = 0;
        __syncthreads();
        int base = hb * EPB;
        int end = min(base + EPB, ETOT);
        for (int e = base + tid; e < end; e += 256)
            atomicAdd(&hist[edge_dst(ei, e) >> 8], 1);
        __syncthreads();
        bh[hb * 256 + tid] = hist[tid];    // tid == bin, coalesced
    }
}

// ---------------------------------------------------------------------------
// Dispatch 2: scan1 v2 — one thread per bin; each walks its HB block-counts
// (coalesced across the 256 threads), block scan of bin totals, rewrite with
// absolute exclusive offsets. 2 barriers total.
__global__ __launch_bounds__(256) void scan1_kernel(int* __restrict__ bh,
                                                    int* __restrict__ rowstart) {
    __shared__ int ws[4];
    int t = threadIdx.x;                   // bin
    int lane = t & 63;
    int w = t >> 6;
    int sum = 0;
#pragma unroll 8
    for (int b = 0; b < HB; ++b) sum += bh[b * 256 + t];
    int x = sum;
#pragma unroll
    for (int off = 1; off < 64; off <<= 1) {
        int tt = __shfl_up(x, off, 64);
        if (lane >= off) x += tt;
    }
    if (lane == 63) ws[w] = x;
    __syncthreads();
    if (t == 0) {
        int s = 0;
#pragma unroll
        for (int j = 0; j < 4; ++j) { int tt = ws[j]; ws[j] = s; s += tt; }
    }
    __syncthreads();
    int base = x - sum + ws[w];            // exclusive across bins
#pragma unroll 8
    for (int b = 0; b < HB; ++b) {
        int v = bh[b * 256 + t];
        bh[b * 256 + t] = base;
        base += v;
    }
    if (t == 0) rowstart[NN] = ETOT;
}

// ---------------------------------------------------------------------------
// MFMA GEMM (h = x @ W^T) + attention dots. 4 waves/block; wave owns 16 nodes
// x 64 cols (4 col-tiles of 16x16), K in 32-chunks. AD written into packed
// ADZ rows (stride 8): [0..3]=AD, [4..7]=Z.
template <int DD>
__device__ __forceinline__ void gemm_att_body(
    int bid, const _Float16* __restrict__ X, const _Float16* __restrict__ Wh,
    const float* __restrict__ attS, const float* __restrict__ attD,
    _Float16* __restrict__ H, float* __restrict__ AS, float* __restrict__ ADZ) {
    constexpr int KB = DD / 32;
    int tid = threadIdx.x;
    int wv = tid >> 6;
    int lane = tid & 63;
    int quad = lane >> 4;
    int n = lane & 15;
    int wbase = bid * 64 + wv * 16;

    int arow = wbase + n;
    if (arow >= NN) arow = NN - 1;          // clamp (stores are guarded)
    half8 a[KB];
#pragma unroll
    for (int kb = 0; kb < KB; ++kb)
        a[kb] = *(const half8*)(X + (size_t)arow * DD + kb * 32 + quad * 8);

    floatx4 c[4];
#pragma unroll
    for (int t = 0; t < 4; ++t) {
        floatx4 acc = {0.f, 0.f, 0.f, 0.f};
#pragma unroll
        for (int kb = 0; kb < KB; ++kb) {
            half8 b = *(const half8*)(Wh + (size_t)(t * 16 + n) * DD + kb * 32 + quad * 8);
            acc = __builtin_amdgcn_mfma_f32_16x16x32_f16(a[kb], b, acc, 0, 0, 0);
        }
        c[t] = acc;
    }

    float as_l[4], ad_l[4];
#pragma unroll
    for (int t = 0; t < 4; ++t) {
        as_l[t] = attS[t * 16 + n];
        ad_l[t] = attD[t * 16 + n];
    }
#pragma unroll
    for (int r = 0; r < 4; ++r) {
        int node = wbase + quad * 4 + r;
        bool ok = node < NN;
#pragma unroll
        for (int t = 0; t < 4; ++t) {
            float h = c[t][r];
            if (ok) H[(size_t)node * 64 + t * 16 + n] = (_Float16)h;
            float vs = h * as_l[t];
            float vd = h * ad_l[t];
#pragma unroll
            for (int off = 8; off; off >>= 1) {
                vs += __shfl_down(vs, off, 16);
                vd += __shfl_down(vd, off, 16);
            }
            if (ok && n == 0) {
                AS[node * 4 + t] = vs;
                ADZ[(size_t)node * 8 + t] = vd;
            }
        }
    }
}

// Dispatch 3: gemm layer 0 (K=128) || scatter1 (LDS-ranked, packed 4B payload).
__global__ __launch_bounds__(256) void gemm0_scatter1_kernel(
    const _Float16* __restrict__ X, const _Float16* __restrict__ Wh,
    const float* __restrict__ attS, const float* __restrict__ attD,
    _Float16* __restrict__ H, float* __restrict__ AS, float* __restrict__ ADZ,
    const int* __restrict__ ei, const int* __restrict__ bh,
    int* __restrict__ tmp) {
    __shared__ int offs[256];
    if (blockIdx.x < GEMMB) {
        gemm_att_body<128>(blockIdx.x, X, Wh, attS, attD, H, AS, ADZ);
    } else {
        int sb = blockIdx.x - GEMMB;       // 0..HB-1
        int tid = threadIdx.x;
        offs[tid] = bh[sb * 256 + tid];    // absolute start (bin, this blk)
        __syncthreads();
        int base = sb * EPB;
        int end = min(base + EPB, ETOT);
        for (int e = base + tid; e < end; e += 256) {
            int d = edge_dst(ei, e);
            int s = edge_src(ei, e);
            int pos = atomicAdd(&offs[d >> 8], 1);   // LDS atomic
            tmp[pos] = s | ((d & 255) << 16);        // 24-bit payload
        }
    }
}

// ---------------------------------------------------------------------------
// Dispatch 4: pass2 v2 — one block per coarse bin, 512 threads. Segment
// staged in LDS once; hist/rank/scatter in LDS; coalesced csr write.
__global__ __launch_bounds__(512) void pass2_kernel(
    const int* __restrict__ tmp, const int* __restrict__ bh,
    int* __restrict__ csr, int* __restrict__ rowstart) {
    __shared__ int pk[SEGCAP];
    __shared__ int outv[SEGCAP];
    __shared__ int h2[256];
    __shared__ int offs[256];
    __shared__ int ws[4];
    int b = blockIdx.x;                    // coarse bin
    int tid = threadIdx.x;
    int A = bh[b];                         // bin-b start (blk 0 offset)
    int Bend = bh[b + 1];                  // next bin start (b<=195<255)
    int n = Bend - A;
    bool fits = (n <= SEGCAP);
    if (tid < 256) h2[tid] = 0;
    __syncthreads();
    if (fits) {
        for (int i = tid; i < n; i += 512) pk[i] = tmp[A + i];
        __syncthreads();
        for (int i = tid; i < n; i += 512) atomicAdd(&h2[pk[i] >> 16], 1);
    } else {
        for (int i = tid; i < n; i += 512) atomicAdd(&h2[tmp[A + i] >> 16], 1);
    }
    __syncthreads();
    int v = 0, x = 0;
    if (tid < 256) {
        int lane = tid & 63;
        v = h2[tid];
        x = v;
#pragma unroll
        for (int off = 1; off < 64; off <<= 1) {
            int t2 = __shfl_up(x, off, 64);
            if (lane >= off) x += t2;
        }
        if (lane == 63) ws[tid >> 6] = x;
    }
    __syncthreads();
    if (tid == 0) {
        int s = 0;
#pragma unroll
        for (int j = 0; j < 4; ++j) { int t2 = ws[j]; ws[j] = s; s += t2; }
    }
    __syncthreads();
    if (tid < 256) {
        int ex = x - v + ws[tid >> 6];     // relative exclusive prefix
        offs[tid] = ex;
        int d = b * 256 + tid;
        if (d < NN) rowstart[d] = A + ex;
    }
    __syncthreads();
    if (fits) {
        for (int i = tid; i < n; i += 512) {
            int p = pk[i];
            int pos = atomicAdd(&offs[p >> 16], 1);
            outv[pos] = p & 0xFFFF;
        }
        __syncthreads();
        for (int i = tid; i < n; i += 512) csr[A + i] = outv[i];  // coalesced
    } else {                                // fallback (never on bench input)
        for (int i = tid; i < n; i += 512) {
            int p = tmp[A + i];
            int pos = atomicAdd(&offs[p >> 16], 1);
            csr[A + pos] = p & 0xFFFF;
        }
    }
}

// ---------------------------------------------------------------------------
// Layer-0 alpha, ORIGINAL edge order: recomputes p from AS/ADZ (identical
// formula+inputs as aggr => identical values), divides by Z, coalesced float4
// store. AD and Z share one 32B row -> one cache line per dst lookup.
__device__ __forceinline__ void alpha_body(
    int bid, const int* __restrict__ ei, const float* __restrict__ AS,
    const float* __restrict__ ADZ, float* __restrict__ alpha_out) {
    int e = bid * 256 + threadIdx.x;
    if (e >= ETOT) return;
    int s = edge_src(ei, e);
    int d = edge_dst(ei, e);
    float4 as = *(const float4*)(AS + (size_t)s * 4);
    const float* row = ADZ + (size_t)d * 8;
    float4 ad = *(const float4*)(row);
    float4 z4 = *(const float4*)(row + 4);
    float l;
    float4 a;
    l = as.x + ad.x; l = l > 0.f ? l : NEGS * l; a.x = __expf(l) / z4.x;
    l = as.y + ad.y; l = l > 0.f ? l : NEGS * l; a.y = __expf(l) / z4.y;
    l = as.z + ad.z; l = l > 0.f ? l : NEGS * l; a.z = __expf(l) / z4.z;
    l = as.w + ad.w; l = l > 0.f ? l : NEGS * l; a.w = __expf(l) / z4.w;
    *(float4*)(alpha_out + (size_t)e * 4) = a;
}

#define SCATB  ((ETOT + 255) / 256)    // 3321 (alpha blocks)

// Merged: gemm layer 1 (K=64, b-buffers) + layer-0 alpha (a-buffers).
__global__ __launch_bounds__(256) void gemm1_alpha_kernel(
    const _Float16* __restrict__ X, const _Float16* __restrict__ Wh,
    const float* __restrict__ attS, const float* __restrict__ attD,
    _Float16* __restrict__ H, float* __restrict__ ASb, float* __restrict__ ADZb,
    const int* __restrict__ ei, const float* __restrict__ ASa,
    const float* __restrict__ ADZa, float* __restrict__ alpha_out) {
    if (blockIdx.x < GEMMB)
        gemm_att_body<64>(blockIdx.x, X, Wh, attS, attD, H, ASb, ADZb);
    else
        alpha_body(blockIdx.x - GEMMB, ei, ASa, ADZa, alpha_out);
}

__global__ __launch_bounds__(256) void gemm2_kernel(
    const _Float16* __restrict__ X, const _Float16* __restrict__ Wh,
    const float* __restrict__ attS, const float* __restrict__ attD,
    _Float16* __restrict__ H, float* __restrict__ AS, float* __restrict__ ADZ) {
    gemm_att_body<64>(blockIdx.x, X, Wh, attS, attD, H, AS, ADZ);
}

// ---------------------------------------------------------------------------
// Per-node aggregation, quarter-wave edge parallelism, single masked 16-wide
// loop (clamped index + p=0 mask).
template <bool WRITE_Z>
__global__ __launch_bounds__(256) void edge_aggr_kernel(
    const _Float16* __restrict__ H, const float* __restrict__ AS,
    float* __restrict__ ADZ,
    const int* __restrict__ rowstart,
    const int* __restrict__ csr,
    const float* __restrict__ bias, const float* __restrict__ gamma,
    const float* __restrict__ beta, const float* __restrict__ mean,
    const float* __restrict__ var, _Float16* __restrict__ Hout) {
    int v = (blockIdx.x * blockDim.x + threadIdx.x) >> 6;
    if (v >= NN) return;
    int lane = threadIdx.x & 63;
    int q = lane >> 4;
    int l16 = lane & 15;
    int head = l16 >> 2;
    int ch4 = l16 * 4;
    float adv = ADZ[(size_t)v * 8 + head];
    int start = rowstart[v];
    int cnt = rowstart[v + 1] - start;   // >= 1 (self loop)
    const int* srow = csr + start;
    int cm1 = cnt - 1;
    float z = 0.f;
    float acc0 = 0.f, acc1 = 0.f, acc2 = 0.f, acc3 = 0.f;
    for (int k = 0; k < cnt; k += 16) {
        int b = k + q * 4;
        int s0 = srow[min(b + 0, cm1)];
        int s1 = srow[min(b + 1, cm1)];
        int s2 = srow[min(b + 2, cm1)];
        int s3 = srow[min(b + 3, cm1)];
        float a0 = AS[(size_t)s0 * 4 + head];
        float a1 = AS[(size_t)s1 * 4 + head];
        float a2 = AS[(size_t)s2 * 4 + head];
        float a3 = AS[(size_t)s3 * 4 + head];
        half4v h0 = *(const half4v*)(H + (size_t)s0 * 64 + ch4);
        half4v h1 = *(const half4v*)(H + (size_t)s1 * 64 + ch4);
        half4v h2 = *(const half4v*)(H + (size_t)s2 * 64 + ch4);
        half4v h3 = *(const half4v*)(H + (size_t)s3 * 64 + ch4);
        float l0 = a0 + adv; l0 = l0 > 0.f ? l0 : NEGS * l0;
        float l1 = a1 + adv; l1 = l1 > 0.f ? l1 : NEGS * l1;
        float l2 = a2 + adv; l2 = l2 > 0.f ? l2 : NEGS * l2;
        float l3 = a3 + adv; l3 = l3 > 0.f ? l3 : NEGS * l3;
        float p0 = (b + 0 < cnt) ? __expf(l0) : 0.f;
        float p1 = (b + 1 < cnt) ? __expf(l1) : 0.f;
        float p2 = (b + 2 < cnt) ? __expf(l2) : 0.f;
        float p3 = (b + 3 < cnt) ? __expf(l3) : 0.f;
        z += (p0 + p1) + (p2 + p3);
        acc0 = fmaf(p0, (float)h0[0], acc0); acc1 = fmaf(p0, (float)h0[1], acc1);
        acc2 = fmaf(p0, (float)h0[2], acc2); acc3 = fmaf(p0, (float)h0[3], acc3);
        acc0 = fmaf(p1, (float)h1[0], acc0); acc1 = fmaf(p1, (float)h1[1], acc1);
        acc2 = fmaf(p1, (float)h1[2], acc2); acc3 = fmaf(p1, (float)h1[3], acc3);
        acc0 = fmaf(p2, (float)h2[0], acc0); acc1 = fmaf(p2, (float)h2[1], acc1);
        acc2 = fmaf(p2, (float)h2[2], acc2); acc3 = fmaf(p2, (float)h2[3], acc3);
        acc0 = fmaf(p3, (float)h3[0], acc0); acc1 = fmaf(p3, (float)h3[1], acc1);
        acc2 = fmaf(p3, (float)h3[2], acc2); acc3 = fmaf(p3, (float)h3[3], acc3);
    }
    // combine the four quarter-wave partial sums
    z    += __shfl_xor(z, 16);    z    += __shfl_xor(z, 32);
    acc0 += __shfl_xor(acc0, 16); acc0 += __shfl_xor(acc0, 32);
    acc1 += __shfl_xor(acc1, 16); acc1 += __shfl_xor(acc1, 32);
    acc2 += __shfl_xor(acc2, 16); acc2 += __shfl_xor(acc2, 32);
    acc3 += __shfl_xor(acc3, 16); acc3 += __shfl_xor(acc3, 32);
    if (q == 0) {
        if (WRITE_Z && (l16 & 3) == 0) ADZ[(size_t)v * 8 + 4 + head] = z;
        float4 bi = *(const float4*)(bias + ch4);
        float4 ga = *(const float4*)(gamma + ch4);
        float4 be = *(const float4*)(beta + ch4);
        float4 mu = *(const float4*)(mean + ch4);
        float4 va = *(const float4*)(var + ch4);
        float r0 = fmaxf(acc0 / z + bi.x, 0.f);
        float r1 = fmaxf(acc1 / z + bi.y, 0.f);
        float r2 = fmaxf(acc2 / z + bi.z, 0.f);
        float r3 = fmaxf(acc3 / z + bi.w, 0.f);
        r0 = ga.x * (r0 - mu.x) * rsqrtf(va.x + BNEPS) + be.x;
        r1 = ga.y * (r1 - mu.y) * rsqrtf(va.y + BNEPS) + be.y;
        r2 = ga.z * (r2 - mu.z) * rsqrtf(va.z + BNEPS) + be.z;
        r3 = ga.w * (r3 - mu.w) * rsqrtf(va.w + BNEPS) + be.w;
        half4v o;
        o[0] = (_Float16)r0;
        o[1] = (_Float16)r1;
        o[2] = (_Float16)r2;
        o[3] = (_Float16)r3;
        *(half4v*)(Hout + (size_t)v * 64 + ch4) = o;
    }
}

// ---------------------------------------------------------------------------
// Mean pool over sorted batch ids (fp16 input): one wave per 16-node chunk,
// local accumulation, atomic flush on graph-id change (max ~25 collisions
// per address — measured fine; do NOT fuse into aggr as per-node atomics).
__global__ __launch_bounds__(256) void pool_kernel(const __half* __restrict__ H,
                                                   const int* __restrict__ batch,
                                                   float* __restrict__ sums,
                                                   int* __restrict__ cnt) {
    int wid = (blockIdx.x * blockDim.x + threadIdx.x) >> 6;
    int lane = threadIdx.x & 63;
    int base = wid * 16;
    if (base >= NN) return;
    int end = min(base + 16, NN);
    int cur = batch[base];
    float acc = 0.f;
    int c0 = 0;
    for (int i = base; i < end; ++i) {
        int g = batch[i];
        if (g != cur) {
            atomicAdd(&sums[cur * 64 + lane], acc);
            if (lane == 0) atomicAdd(&cnt[cur], c0);
            cur = g; acc = 0.f; c0 = 0;
        }
        acc += __half2float(H[(size_t)i * 64 + lane]);
        c0++;
    }
    atomicAdd(&sums[cur * 64 + lane], acc);
    if (lane == 0) atomicAdd(&cnt[cur], c0);
}

__global__ void fc_kernel(const float* __restrict__ sums, const int* __restrict__ cnt,
                          const float* __restrict__ fcW, const float* __restrict__ fcb,
                          float* __restrict__ out) {
    int g = (blockIdx.x * blockDim.x + threadIdx.x) >> 6;
    int lane = threadIdx.x & 63;
    if (g >= NG) return;
    float c = fmaxf((float)cnt[g], 1.f);
    float val = (sums[g * 64 + lane] / c) * fcW[lane];
#pragma unroll
    for (int off = 32; off; off >>= 1) val += __shfl_down(val, off, 64);
    if (lane == 0) out[g] = 1.f / (1.f + expf(-(val + fcb[0])));
}

// ---------------------------------------------------------------------------
extern "C" void kernel_launch(void* const* d_in, const int* in_sizes, int n_in,
                              void* d_out, int out_size, void* d_ws, size_t ws_size,
                              hipStream_t stream) {
    const float* x   = (const float*)d_in[0];
    const int* ei    = (const int*)d_in[1];
    const int* batch = (const int*)d_in[2];
    const float* W[3], *attS[3], *attD[3], *bias[3], *gamma[3], *beta[3], *mean[3], *var[3];
    for (int l = 0; l < 3; ++l) {
        W[l]     = (const float*)d_in[3 + 8 * l + 0];
        attS[l]  = (const float*)d_in[3 + 8 * l + 1];
        attD[l]  = (const float*)d_in[3 + 8 * l + 2];
        bias[l]  = (const float*)d_in[3 + 8 * l + 3];
        gamma[l] = (const float*)d_in[3 + 8 * l + 4];
        beta[l]  = (const float*)d_in[3 + 8 * l + 5];
        mean[l]  = (const float*)d_in[3 + 8 * l + 6];
        var[l]   = (const float*)d_in[3 + 8 * l + 7];
    }
    const float* fcW = (const float*)d_in[27];
    const float* fcb = (const float*)d_in[28];
    float* out = (float*)d_out;               // [128] pooled sigmoid
    float* alpha_out = (float*)d_out + NG;    // [850000*4] layer-0 alpha

    // Workspace carve-up (256B aligned)
    char* p = (char*)d_ws;
    auto carve = [&](size_t bytes) {
        char* q = p;
        p += (bytes + 255) & ~(size_t)255;
        return q;
    };
    _Float16* Xh    = (_Float16*)carve(sizeof(_Float16) * NN * INDIM);
    _Float16* Wh    = (_Float16*)carve(sizeof(_Float16) * 16384);
    _Float16* Hh    = (_Float16*)carve(sizeof(_Float16) * NN * 64);  // gemm out
    _Float16* Hn    = (_Float16*)carve(sizeof(_Float16) * NN * 64);  // aggr out
    float* ASa      = (float*)carve(sizeof(float) * NN * 4);   // layers 0,2
    float* ADZa     = (float*)carve(sizeof(float) * NN * 8);   // [0..3]=AD [4..7]=Z
    float* ASb      = (float*)carve(sizeof(float) * NN * 4);   // layer 1
    float* ADZb     = (float*)carve(sizeof(float) * NN * 8);
    int*   rowstart = (int*)carve(sizeof(int) * (NN + 1));
    int*   bh       = (int*)carve(sizeof(int) * 256 * HB);     // blk-major hists
    int*   tmp      = (int*)carve(sizeof(int) * ETOT);         // packed pass-1
    int*   csr      = (int*)carve(sizeof(int) * ETOT);
    float* psums    = (float*)carve(sizeof(float) * NG * 64);
    int*   pcnt     = (int*)carve(sizeof(int) * NG);

    int edgeBlocks = (NN * 64 + 255) / 256;

    // 1. prep (X/W converts, psums/pcnt zero) || coarse histogram (LDS)
    prep_hist_kernel<<<PREPWB + HB, 256, 0, stream>>>(
        x, W[0], W[1], W[2], Xh, Wh, psums, pcnt, ei, bh);

    // 2. scan of block histograms -> absolute offsets (+ rowstart[NN])
    scan1_kernel<<<1, 256, 0, stream>>>(bh, rowstart);

    // 3. gemm layer 0 || bin-grouping scatter into tmp (LDS-ranked, 4B)
    gemm0_scatter1_kernel<<<GEMMB + HB, 256, 0, stream>>>(
        Xh, Wh, attS[0], attD[0], Hh, ASa, ADZa, ei, bh, tmp);

    // 4. per-bin low-byte sort in LDS -> rowstart + final csr (coalesced IO)
    pass2_kernel<<<PASS2B, 512, 0, stream>>>(tmp, bh, csr, rowstart);

    // 5. aggr layer 0 (writes Z into ADZa, Hn)
    edge_aggr_kernel<true><<<edgeBlocks, 256, 0, stream>>>(
        Hh, ASa, ADZa, rowstart, csr,
        bias[0], gamma[0], beta[0], mean[0], var[0], Hn);

    // 6. gemm layer 1 (b-buffers) || layer-0 alpha (a-buffers)
    gemm1_alpha_kernel<<<GEMMB + SCATB, 256, 0, stream>>>(
        Hn, Wh + 8192, attS[1], attD[1], Hh, ASb, ADZb,
        ei, ASa, ADZa, alpha_out);

    // 7. aggr layer 1
    edge_aggr_kernel<false><<<edgeBlocks, 256, 0, stream>>>(
        Hh, ASb, ADZb, rowstart, csr,
        bias[1], gamma[1], beta[1], mean[1], var[1], Hn);

    // 8. gemm layer 2 (a-buffers again — alpha completed in step 6)
    gemm2_kernel<<<GEMMB, 256, 0, stream>>>(
        Hn, Wh + 12288, attS[2], attD[2], Hh, ASa, ADZa);

    // 9. aggr layer 2 -> Hn
    edge_aggr_kernel<false><<<edgeBlocks, 256, 0, stream>>>(
        Hh, ASa, ADZa, rowstart, csr,
        bias[2], gamma[2], beta[2], mean[2], var[2], Hn);

    // 10. pool (streaming, low-contention flush atomics)
    int poolWaves = (NN + 15) / 16;
    pool_kernel<<<(poolWaves * 64 + 255) / 256, 256, 0, stream>>>(
        (const __half*)Hn, batch, psums, pcnt);

    // 11. FC
    fc_kernel<<<(NG * 64 + 255) / 256, 256, 0, stream>>>(psums, pcnt, fcW, fcb, out);
}